// Round 1
// baseline (103.983 us; speedup 1.0000x reference)
//
#include <hip/hip_runtime.h>

#define IW 1024
#define IH 1024
#define BATCH 8
#define TILE_W 128
#define TILE_H 32
#define RW 140   // staged region width  (x: gx0-4 .. gx0+135), float4-aligned
#define RH 36    // staged region height (y: gy0-2 .. gy0+33)
#define HRW 68   // half-res ed stride (66 cols used)
#define NBLK ((IW/TILE_W)*(IH/TILE_H)*BATCH)  // 8*32*8 = 2048

__global__ __launch_bounds__(256) void gloss_main(const float* __restrict__ out_img,
                                                  const float* __restrict__ tgt_img,
                                                  float* __restrict__ partials) {
    __shared__ float t_s[RH * RW];
    __shared__ float o_s[RH * RW];
    __shared__ float ed_s[18 * HRW];
    __shared__ float red_s[4];

    const int tid = threadIdx.x;
    const int bx = blockIdx.x, by = blockIdx.y, bz = blockIdx.z;
    const int gx0 = bx * TILE_W;
    const int gy0 = by * TILE_H;
    const float* tb = tgt_img + (size_t)bz * (IH * IW);
    const float* ob = out_img + (size_t)bz * (IH * IW);

    // ---- Stage t,o tiles (with halo 2) into LDS, zero-fill out-of-image ----
    const int NV = RH * (RW / 4);  // 36*35 = 1260 float4 slots per array
    for (int idx = tid; idx < NV; idx += 256) {
        int r  = idx / (RW / 4);
        int c4 = idx - r * (RW / 4);
        int gy = gy0 - 2 + r;
        int gx = gx0 - 4 + c4 * 4;
        float4 tv, ov;
        if (gy >= 0 && gy < IH && gx >= 0 && gx + 3 < IW) {
            tv = *(const float4*)(tb + (size_t)gy * IW + gx);
            ov = *(const float4*)(ob + (size_t)gy * IW + gx);
        } else {
            float tt[4], oo[4];
#pragma unroll
            for (int j = 0; j < 4; ++j) {
                int x = gx + j;
                bool ok = (gy >= 0 && gy < IH && x >= 0 && x < IW);
                tt[j] = ok ? tb[(size_t)gy * IW + x] : 0.f;
                oo[j] = ok ? ob[(size_t)gy * IW + x] : 0.f;
            }
            tv = make_float4(tt[0], tt[1], tt[2], tt[3]);
            ov = make_float4(oo[0], oo[1], oo[2], oo[3]);
        }
        *(float4*)(t_s + r * RW + c4 * 4) = tv;
        *(float4*)(o_s + r * RW + c4 * 4) = ov;
    }
    __syncthreads();

    // ---- Build half-res e_d = max4(t) - max4(o), 18 x 66 with halo 1 ----
    for (int idx = tid; idx < 18 * 66; idx += 256) {
        int hr = idx / 66;
        int hc = idx - hr * 66;
        int fr = 2 * hr;
        int fc = 2 * hc + 2;           // even -> 8B aligned
        const float* tp = t_s + fr * RW + fc;
        const float* op = o_s + fr * RW + fc;
        float2 ta = *(const float2*)(tp);
        float2 tc = *(const float2*)(tp + RW);
        float2 oa = *(const float2*)(op);
        float2 oc = *(const float2*)(op + RW);
        float td = fmaxf(fmaxf(ta.x, ta.y), fmaxf(tc.x, tc.y));
        float od = fmaxf(fmaxf(oa.x, oa.y), fmaxf(oc.x, oc.y));
        ed_s[hr * HRW + hc] = td - od;
    }
    __syncthreads();

    float gsum = 0.f, psum = 0.f, gdsum = 0.f;

    // ---- Full-res: grad8(e) squared sum + pixel loss, sliding 3x3 window ----
    {
        const int xl  = tid & (TILE_W - 1);
        const int grp = tid >> 7;          // 0..1, 16 rows each
        const int col = xl + 4;
        const int row0 = grp * 16 + 2;     // LDS row of first pixel
        float em0, em1, em2, ec0, ec1, ec2;
        {
            const int rA = row0 - 1, rB = row0;
            em0 = t_s[rA * RW + col - 1] - o_s[rA * RW + col - 1];
            em1 = t_s[rA * RW + col    ] - o_s[rA * RW + col    ];
            em2 = t_s[rA * RW + col + 1] - o_s[rA * RW + col + 1];
            ec0 = t_s[rB * RW + col - 1] - o_s[rB * RW + col - 1];
            ec1 = t_s[rB * RW + col    ] - o_s[rB * RW + col    ];
            ec2 = t_s[rB * RW + col + 1] - o_s[rB * RW + col + 1];
        }
#pragma unroll
        for (int i = 0; i < 16; ++i) {
            const int rN = row0 + i + 1;
            float ep0 = t_s[rN * RW + col - 1] - o_s[rN * RW + col - 1];
            float ep1 = t_s[rN * RW + col    ] - o_s[rN * RW + col    ];
            float ep2 = t_s[rN * RW + col + 1] - o_s[rN * RW + col + 1];
            float c = ec1, d;
            d = c - em0; gsum += d * d;
            d = c - em1; gsum += d * d;
            d = c - em2; gsum += d * d;
            d = c - ec0; gsum += d * d;
            d = c - ec2; gsum += d * d;
            d = c - ep0; gsum += d * d;
            d = c - ep1; gsum += d * d;
            d = c - ep2; gsum += d * d;
            psum += c * c;
            em0 = ec0; em1 = ec1; em2 = ec2;
            ec0 = ep0; ec1 = ep1; ec2 = ep2;
        }
    }

    // ---- Half-res: grad8(e_d) squared sum, 64x16 half-pixels per block ----
    {
        const int hxl  = tid & 63;
        const int hgrp = tid >> 6;         // 0..3, 4 rows each
        const int col  = hxl + 1;
        const int row0 = hgrp * 4 + 1;
        float em0 = ed_s[(row0 - 1) * HRW + col - 1];
        float em1 = ed_s[(row0 - 1) * HRW + col    ];
        float em2 = ed_s[(row0 - 1) * HRW + col + 1];
        float ec0 = ed_s[row0 * HRW + col - 1];
        float ec1 = ed_s[row0 * HRW + col    ];
        float ec2 = ed_s[row0 * HRW + col + 1];
#pragma unroll
        for (int i = 0; i < 4; ++i) {
            const int rN = row0 + i + 1;
            float ep0 = ed_s[rN * HRW + col - 1];
            float ep1 = ed_s[rN * HRW + col    ];
            float ep2 = ed_s[rN * HRW + col + 1];
            float c = ec1, d;
            d = c - em0; gdsum += d * d;
            d = c - em1; gdsum += d * d;
            d = c - em2; gdsum += d * d;
            d = c - ec0; gdsum += d * d;
            d = c - ec2; gdsum += d * d;
            d = c - ep0; gdsum += d * d;
            d = c - ep1; gdsum += d * d;
            d = c - ep2; gdsum += d * d;
            em0 = ec0; em1 = ec1; em2 = ec2;
            ec0 = ep0; ec1 = ep1; ec2 = ep2;
        }
    }

    // ---- Weighted block reduction ----
    // N = 8*1024*1024; counts: g: 8N, p: N, gd: 8*(N/4) = 2N
    const float WG = 1.f / (8.f * 8388608.f);
    const float WP = 1.f / 8388608.f;
    const float WD = 1.f / (2.f * 8388608.f);
    float partial = gsum * WG + psum * WP + gdsum * WD;
#pragma unroll
    for (int off = 32; off > 0; off >>= 1)
        partial += __shfl_down(partial, off, 64);
    const int lane = tid & 63, wid = tid >> 6;
    if (lane == 0) red_s[wid] = partial;
    __syncthreads();
    if (tid == 0) {
        int bid = (bz * gridDim.y + by) * gridDim.x + bx;
        partials[bid] = red_s[0] + red_s[1] + red_s[2] + red_s[3];
    }
}

__global__ __launch_bounds__(256) void gloss_reduce(const float* __restrict__ partials,
                                                    float* __restrict__ out) {
    __shared__ float red_s[4];
    const int tid = threadIdx.x;
    float s = 0.f;
    for (int i = tid; i < NBLK; i += 256) s += partials[i];
#pragma unroll
    for (int off = 32; off > 0; off >>= 1)
        s += __shfl_down(s, off, 64);
    if ((tid & 63) == 0) red_s[tid >> 6] = s;
    __syncthreads();
    if (tid == 0) out[0] = red_s[0] + red_s[1] + red_s[2] + red_s[3];
}

extern "C" void kernel_launch(void* const* d_in, const int* in_sizes, int n_in,
                              void* d_out, int out_size, void* d_ws, size_t ws_size,
                              hipStream_t stream) {
    const float* outp = (const float*)d_in[0];   // "output"
    const float* tgtp = (const float*)d_in[1];   // "target"
    float* ws = (float*)d_ws;                    // >= NBLK floats
    dim3 grid(IW / TILE_W, IH / TILE_H, BATCH);
    gloss_main<<<grid, 256, 0, stream>>>(outp, tgtp, ws);
    gloss_reduce<<<1, 256, 0, stream>>>(ws, (float*)d_out);
}

// Round 2
// 99.823 us; speedup vs baseline: 1.0417x; 1.0417x over previous
//
#include <hip/hip_runtime.h>

#define IW 1024
#define IH 1024
#define BATCH 8
#define TILE_W 128
#define TILE_H 32
#define RW 140   // staged e width  (x: gx0-4 .. gx0+135), float4-aligned
#define RH 36    // staged e height (y: gy0-2 .. gy0+33)
#define HED 72   // ed stride; centers at cols 4..67 (b128-aligned)
#define NBLK ((IW/TILE_W)*(IH/TILE_H)*BATCH)  // 8*32*8 = 2048

__global__ __launch_bounds__(256) void gloss_main(const float* __restrict__ out_img,
                                                  const float* __restrict__ tgt_img,
                                                  float* __restrict__ partials) {
    __shared__ float e_s[RH * RW];     // e = t - o, full res
    __shared__ float ed_s[18 * HED];   // e_d = max4(t) - max4(o), half res
    __shared__ float red_s[4];

    const int tid = threadIdx.x;
    const int bx = blockIdx.x, by = blockIdx.y, bz = blockIdx.z;
    const int gx0 = bx * TILE_W;
    const int gy0 = by * TILE_H;
    const float* tb = tgt_img + (size_t)bz * (IH * IW);
    const float* ob = out_img + (size_t)bz * (IH * IW);

    // ---- Stage: load t,o row-pairs, write e rows + pooled ed in one pass ----
    // 18 row-pairs x 35 float4 columns = 630 tasks
    for (int idx = tid; idx < 630; idx += 256) {
        int rp = idx / 35;
        int c4 = idx - rp * 35;
        int r0 = 2 * rp;                 // LDS row of first row in pair
        int gyA = gy0 - 2 + r0;          // global rows gyA, gyA+1
        int gx  = gx0 - 4 + 4 * c4;
        float4 t0, t1, o0, o1;
        bool xin = (gx >= 0) && (gx + 3 < IW);
        bool yAin = (gyA >= 0) && (gyA < IH);
        bool yBin = (gyA + 1 >= 0) && (gyA + 1 < IH);
        if (xin && yAin && yBin) {
            const float* tp = tb + (size_t)gyA * IW + gx;
            const float* op = ob + (size_t)gyA * IW + gx;
            t0 = *(const float4*)tp;       t1 = *(const float4*)(tp + IW);
            o0 = *(const float4*)op;       o1 = *(const float4*)(op + IW);
        } else {
            float tt0[4], tt1[4], oo0[4], oo1[4];
#pragma unroll
            for (int j = 0; j < 4; ++j) {
                int x = gx + j;
                bool okx = (x >= 0) && (x < IW);
                bool okA = okx && yAin, okB = okx && yBin;
                tt0[j] = okA ? tb[(size_t)gyA * IW + x] : 0.f;
                oo0[j] = okA ? ob[(size_t)gyA * IW + x] : 0.f;
                tt1[j] = okB ? tb[(size_t)(gyA + 1) * IW + x] : 0.f;
                oo1[j] = okB ? ob[(size_t)(gyA + 1) * IW + x] : 0.f;
            }
            t0 = make_float4(tt0[0], tt0[1], tt0[2], tt0[3]);
            t1 = make_float4(tt1[0], tt1[1], tt1[2], tt1[3]);
            o0 = make_float4(oo0[0], oo0[1], oo0[2], oo0[3]);
            o1 = make_float4(oo1[0], oo1[1], oo1[2], oo1[3]);
        }
        float4 e0 = make_float4(t0.x - o0.x, t0.y - o0.y, t0.z - o0.z, t0.w - o0.w);
        float4 e1 = make_float4(t1.x - o1.x, t1.y - o1.y, t1.z - o1.z, t1.w - o1.w);
        *(float4*)(e_s + r0 * RW + 4 * c4) = e0;
        *(float4*)(e_s + (r0 + 1) * RW + 4 * c4) = e1;
        // pooled: pair A = elems 0,1 ; pair B = elems 2,3
        float tdA = fmaxf(fmaxf(t0.x, t0.y), fmaxf(t1.x, t1.y));
        float tdB = fmaxf(fmaxf(t0.z, t0.w), fmaxf(t1.z, t1.w));
        float odA = fmaxf(fmaxf(o0.x, o0.y), fmaxf(o1.x, o1.y));
        float odB = fmaxf(fmaxf(o0.z, o0.w), fmaxf(o1.z, o1.w));
        // ed index: A -> 2*c4+2, B -> 2*c4+3 (layout shifted +3; centers 4..67)
        if (c4 <= 33) {
            ed_s[rp * HED + 2 * c4 + 2] = tdA - odA;
            ed_s[rp * HED + 2 * c4 + 3] = tdB - odB;
        }
    }
    __syncthreads();

    float gsum = 0.f, psum = 0.f, gdsum = 0.f;

    // ---- Full-res grad8 + pixel loss: 4 px/thread/row, sliding 3-row window ----
    {
        const int cg = tid & 31;          // 32 col-groups x 4 px = 128 cols
        const int rg = tid >> 5;          // 8 row-groups x 4 rows
        const int col0 = 4 + 4 * cg;
        const int row0 = 2 + 4 * rg;
        float rm[6], rc[6], rp_[6];
        {
            const float* p = e_s + (row0 - 1) * RW + col0;
            float4 v = *(const float4*)p;
            rm[0] = p[-1]; rm[1] = v.x; rm[2] = v.y; rm[3] = v.z; rm[4] = v.w; rm[5] = p[4];
            p = e_s + row0 * RW + col0;
            v = *(const float4*)p;
            rc[0] = p[-1]; rc[1] = v.x; rc[2] = v.y; rc[3] = v.z; rc[4] = v.w; rc[5] = p[4];
        }
#pragma unroll
        for (int i = 0; i < 4; ++i) {
            const float* p = e_s + (row0 + i + 1) * RW + col0;
            float4 v = *(const float4*)p;
            rp_[0] = p[-1]; rp_[1] = v.x; rp_[2] = v.y; rp_[3] = v.z; rp_[4] = v.w; rp_[5] = p[4];
#pragma unroll
            for (int j = 0; j < 4; ++j) {
                float c = rc[j + 1], d;
                d = c - rm[j];      gsum += d * d;
                d = c - rm[j + 1];  gsum += d * d;
                d = c - rm[j + 2];  gsum += d * d;
                d = c - rc[j];      gsum += d * d;
                d = c - rc[j + 2];  gsum += d * d;
                d = c - rp_[j];     gsum += d * d;
                d = c - rp_[j + 1]; gsum += d * d;
                d = c - rp_[j + 2]; gsum += d * d;
                psum += c * c;
            }
#pragma unroll
            for (int k = 0; k < 6; ++k) { rm[k] = rc[k]; rc[k] = rp_[k]; }
        }
    }

    // ---- Half-res grad8: 4 px/thread, one row each ----
    {
        const int hcg = tid & 15;         // 16 col-groups x 4 px = 64 cols
        const int hrg = tid >> 4;         // 16 rows
        const int col0 = 4 + 4 * hcg;
        const int row = 1 + hrg;
        float a[6], b[6], c6[6];
        const float* p = ed_s + (row - 1) * HED + col0;
        float4 v = *(const float4*)p;
        a[0] = p[-1]; a[1] = v.x; a[2] = v.y; a[3] = v.z; a[4] = v.w; a[5] = p[4];
        p = ed_s + row * HED + col0;
        v = *(const float4*)p;
        b[0] = p[-1]; b[1] = v.x; b[2] = v.y; b[3] = v.z; b[4] = v.w; b[5] = p[4];
        p = ed_s + (row + 1) * HED + col0;
        v = *(const float4*)p;
        c6[0] = p[-1]; c6[1] = v.x; c6[2] = v.y; c6[3] = v.z; c6[4] = v.w; c6[5] = p[4];
#pragma unroll
        for (int j = 0; j < 4; ++j) {
            float c = b[j + 1], d;
            d = c - a[j];      gdsum += d * d;
            d = c - a[j + 1];  gdsum += d * d;
            d = c - a[j + 2];  gdsum += d * d;
            d = c - b[j];      gdsum += d * d;
            d = c - b[j + 2];  gdsum += d * d;
            d = c - c6[j];     gdsum += d * d;
            d = c - c6[j + 1]; gdsum += d * d;
            d = c - c6[j + 2]; gdsum += d * d;
        }
    }

    // ---- Weighted block reduction ----
    const float WG = 1.f / (8.f * 8388608.f);
    const float WP = 1.f / 8388608.f;
    const float WD = 1.f / (2.f * 8388608.f);
    float partial = gsum * WG + psum * WP + gdsum * WD;
#pragma unroll
    for (int off = 32; off > 0; off >>= 1)
        partial += __shfl_down(partial, off, 64);
    const int lane = tid & 63, wid = tid >> 6;
    if (lane == 0) red_s[wid] = partial;
    __syncthreads();
    if (tid == 0) {
        int bid = (bz * gridDim.y + by) * gridDim.x + bx;
        partials[bid] = red_s[0] + red_s[1] + red_s[2] + red_s[3];
    }
}

__global__ __launch_bounds__(256) void gloss_reduce(const float* __restrict__ partials,
                                                    float* __restrict__ out) {
    __shared__ float red_s[4];
    const int tid = threadIdx.x;
    float s = 0.f;
    for (int i = tid; i < NBLK; i += 256) s += partials[i];
#pragma unroll
    for (int off = 32; off > 0; off >>= 1)
        s += __shfl_down(s, off, 64);
    if ((tid & 63) == 0) red_s[tid >> 6] = s;
    __syncthreads();
    if (tid == 0) out[0] = red_s[0] + red_s[1] + red_s[2] + red_s[3];
}

extern "C" void kernel_launch(void* const* d_in, const int* in_sizes, int n_in,
                              void* d_out, int out_size, void* d_ws, size_t ws_size,
                              hipStream_t stream) {
    const float* outp = (const float*)d_in[0];   // "output"
    const float* tgtp = (const float*)d_in[1];   // "target"
    float* ws = (float*)d_ws;                    // >= NBLK floats
    dim3 grid(IW / TILE_W, IH / TILE_H, BATCH);
    gloss_main<<<grid, 256, 0, stream>>>(outp, tgtp, ws);
    gloss_reduce<<<1, 256, 0, stream>>>(ws, (float*)d_out);
}